// Round 12
// baseline (2334.231 us; speedup 1.0000x reference)
//
#include <hip/hip_runtime.h>
#include <math.h>

// Batched exact Hungarian (Jonker-Volgenant). One wave per batch; lane l owns
// contiguous columns j = 4l..4l+3 (jj = 4l+k+1): lowest-jj tie-break ==
// prefer-left local tree then lowest-lane ballot == jnp.argmin first-occur.
//
// Round-12: FULLY LDS-FREE. r11 showed the Dijkstra iteration's spec-reads
// were already hidden; the remaining long-latency serial work is the per-row
// augment walk (2 dependent scattered ds_reads per step ~480cy) + way-flush
// + 2 barriers per row. All replaced with register mirrors + readlane:
//   wayr[k]  (per-lane)      way[4l+k]
//   pl[k]                     p[4l+k+1]
//   ur[k]                     u[p[4l+k+1]]  (row-start value)
//   prx..prw[k]               pred[p[4l+k+1]]
//   qx..qw[k]                 pred row 4l+k (for row-start pr pulls)
// Walk step: uniform 3-cndmask select + v_readlane (no LDS). Zero
// __shared__, zero barriers. All consumed float values bit-identical to
// r11 (validated absmax 0.0); same mark/deferred-u/v/fast-sqrt machinery.
//
// Output dtype: harness reads d_out as float32; col4row stored as floats.

#define NB   32
#define NN   256
#define ND   4
#define NPT  4
#define INFV 1e9f

#if __has_builtin(__builtin_amdgcn_sqrtf)
__device__ __forceinline__ float fast_sqrtf(float x) { return __builtin_amdgcn_sqrtf(x); }
#else
__device__ __forceinline__ float fast_sqrtf(float x) {
    float r; asm volatile("v_sqrt_f32 %0, %1" : "=v"(r) : "v"(x)); return r;
}
#endif

__device__ __forceinline__ float wave_min_bcast(float x) {
    // 64-lane min in 5 dependent steps (min3 ladder); fill=1e9 never wins.
    const int fill = __float_as_int(INFV);
    int a, c;
    a = __builtin_amdgcn_update_dpp(fill, __float_as_int(x), 0x111, 0xF, 0xF, false); // row_shr:1
    c = __builtin_amdgcn_update_dpp(fill, __float_as_int(x), 0x112, 0xF, 0xF, false); // row_shr:2
    x = fminf(x, fminf(__int_as_float(a), __int_as_float(c)));      // cover 3
    a = __builtin_amdgcn_update_dpp(fill, __float_as_int(x), 0x113, 0xF, 0xF, false); // row_shr:3
    c = __builtin_amdgcn_update_dpp(fill, __float_as_int(x), 0x116, 0xF, 0xF, false); // row_shr:6
    x = fminf(x, fminf(__int_as_float(a), __int_as_float(c)));      // cover 9
    a = __builtin_amdgcn_update_dpp(fill, __float_as_int(x), 0x117, 0xF, 0xF, false); // row_shr:7
    x = fminf(x, __int_as_float(a));                                // cover 16
    a = __builtin_amdgcn_update_dpp(fill, __float_as_int(x), 0x142, 0xF, 0xF, false); // row_bcast:15
    x = fminf(x, __int_as_float(a));
    a = __builtin_amdgcn_update_dpp(fill, __float_as_int(x), 0x143, 0xF, 0xF, false); // row_bcast:31
    x = fminf(x, __int_as_float(a));                                // lane63 = global
    return __int_as_float(__builtin_amdgcn_readlane(__float_as_int(x), 63));
}

__device__ __forceinline__ float readlane_f(float v, int lane) {
    return __int_as_float(__builtin_amdgcn_readlane(__float_as_int(v), lane));
}
__device__ __forceinline__ int readlane_i(int v, int lane) {
    return __builtin_amdgcn_readlane(v, lane);
}
// select a[kk] for wave-uniform kk (3 cndmasks, 2-level)
__device__ __forceinline__ float self4(const float* a, int kk) {
    float u0 = (kk & 1) ? a[1] : a[0];
    float u1 = (kk & 1) ? a[3] : a[2];
    return (kk & 2) ? u1 : u0;
}
__device__ __forceinline__ int seli4(const int* a, int kk) {
    int u0 = (kk & 1) ? a[1] : a[0];
    int u1 = (kk & 1) ? a[3] : a[2];
    return (kk & 2) ? u1 : u0;
}

__global__ __launch_bounds__(64) void hungarian_kernel(
    const float* __restrict__ pred, const float* __restrict__ gt,
    float* __restrict__ out)
{
#pragma clang fp contract(off)
    const int b    = blockIdx.x;
    const int lane = threadIdx.x;

    const float* pb = pred + (size_t)b * NN * ND;
    const float* gb = gt   + (size_t)b * NN * ND;

    // gt mirrors for owned columns 4l+k, pred-row mirrors for rows 4l+k
    float gx[NPT], gy[NPT], gz[NPT], gw[NPT];
    float qx[NPT], qy[NPT], qz[NPT], qw[NPT];
    #pragma unroll
    for (int k = 0; k < NPT; ++k) {
        float4 gv = ((const float4*)gb)[4 * lane + k];
        gx[k] = gv.x; gy[k] = gv.y; gz[k] = gv.z; gw[k] = gv.w;
        float4 pv = ((const float4*)pb)[4 * lane + k];
        qx[k] = pv.x; qy[k] = pv.y; qz[k] = pv.z; qw[k] = pv.w;
    }
    // column potentials + mirrors of the matched row's u and pred
    float v[NPT], ur[NPT], prx[NPT], pry[NPT], prz[NPT], prw[NPT];
    int pl[NPT];
    #pragma unroll
    for (int k = 0; k < NPT; ++k) {
        v[k] = 0.f; pl[k] = 0; ur[k] = 0.f;
        prx[k] = 0.f; pry[k] = 0.f; prz[k] = 0.f; prw[k] = 0.f;
    }
    const float FINF = __int_as_float(0x7f800000);   // +inf
    const float NINF = __int_as_float(0xff800000);   // -inf

    for (int i = 1; i <= NN; ++i) {
        // row-start: pull pred row i from q-mirrors (wave-uniform owner)
        const int im1 = i - 1, kki = im1 & 3, owi = im1 >> 2;
        float4 pr0;
        pr0.x = readlane_f(self4(qx, kki), owi);
        pr0.y = readlane_f(self4(qy, kki), owi);
        pr0.z = readlane_f(self4(qz, kki), owi);
        pr0.w = readlane_f(self4(qw, kki), owi);
        float4 pr = pr0;

        int codes[NPT];                    // (jj | pl<<12), constant per row
        #pragma unroll
        for (int k = 0; k < NPT; ++k) codes[k] = (4 * lane + k + 1) | (pl[k] << 12);
        float minv[NPT], vm[NPT], ucol[NPT], mcol[NPT];
        int   wayr[NPT];
        #pragma unroll
        for (int k = 0; k < NPT; ++k) {
            minv[k] = INFV; vm[k] = v[k]; ucol[k] = 0.f; mcol[k] = 0.f; wayr[k] = 0;
        }
        float u_i = 0.f;                          // running sum of deltas == ref u[i]
        int   j1  = 0;
        float ui  = 0.f;                          // u[p[j1]] row-start value
        int   i0n = i;

        for (int it = 0; it < NN + 2; ++it) {
            // branchless mark: jm1=-1 on first iter matches no lane
            const int   jm1 = j1 - 1;             // wave-uniform
            const float bu  = ui - u_i;
            #pragma unroll
            for (int k = 0; k < NPT; ++k) {
                bool hit = (4 * lane + k) == jm1;
                vm[k]   = hit ? NINF : vm[k];     // freezes wayr; cur=+inf
                minv[k] = hit ? FINF : minv[k];   // masks argmin
                ucol[k] = hit ? bu   : ucol[k];   // u_new = ucol + u_i_end
                mcol[k] = hit ? u_i  : mcol[k];   // v_new = (v - u_i_end) + mcol
            }
            // scan owned columns; fma ss + fast sqrt (decisions only)
            #pragma unroll
            for (int k = 0; k < NPT; ++k) {
                float dx = pr.x - gx[k], dy = pr.y - gy[k];
                float dz = pr.z - gz[k], dw = pr.w - gw[k];
                float ss = dx * dx;
                ss = __builtin_fmaf(dy, dy, ss);
                ss = __builtin_fmaf(dz, dz, ss);
                ss = __builtin_fmaf(dw, dw, ss);
                float cur = (fast_sqrtf(ss) - ui) - vm[k];   // used: +inf
                bool upd = cur < minv[k];
                wayr[k] = upd ? j1 : wayr[k];
                minv[k] = fminf(minv[k], cur);
            }
            // 2-level tree argmin with payloads (strict <, prefer-left)
            bool s01 = minv[1] < minv[0];
            float v01 = s01 ? minv[1] : minv[0];
            int   c01 = s01 ? codes[1] : codes[0];
            float u01 = s01 ? ur[1] : ur[0];
            float x01 = s01 ? prx[1] : prx[0];
            float y01 = s01 ? pry[1] : pry[0];
            float z01 = s01 ? prz[1] : prz[0];
            float w01 = s01 ? prw[1] : prw[0];
            bool s23 = minv[3] < minv[2];
            float v23 = s23 ? minv[3] : minv[2];
            int   c23 = s23 ? codes[3] : codes[2];
            float u23 = s23 ? ur[3] : ur[2];
            float x23 = s23 ? prx[3] : prx[2];
            float y23 = s23 ? pry[3] : pry[2];
            float z23 = s23 ? prz[3] : prz[2];
            float w23 = s23 ? prw[3] : prw[2];
            bool sF  = v23 < v01;
            float best       = sF ? v23 : v01;
            int   code_local = sF ? c23 : c01;
            float usel = sF ? u23 : u01;
            float xsel = sF ? x23 : x01;
            float ysel = sF ? y23 : y01;
            float zsel = sF ? z23 : z01;
            float wsel = sF ? w23 : w01;
            // wave argmin: value min via DPP; owner = lowest lane at min
            const float gmin = wave_min_bcast(best);
            unsigned long long msk = __ballot(best == gmin);
            int owner = __ffsll(msk) - 1;
            int code  = readlane_i(code_local, owner);
            int j1n   = code & 0xFFF;
            i0n       = code >> 12;
            // minimal updates: minv -= delta (used stay +inf); u_i += delta
            const float delta = gmin;
            #pragma unroll
            for (int k = 0; k < NPT; ++k) minv[k] -= delta;
            u_i += delta;
            j1 = j1n;
            if (i0n == 0) break;                  // free column (updates done)
            // pull winner's mirrored values (no LDS)
            ui   = readlane_f(usel, owner);
            pr.x = readlane_f(xsel, owner);
            pr.y = readlane_f(ysel, owner);
            pr.z = readlane_f(zsel, owner);
            pr.w = readlane_f(wsel, owner);
        }

        // deferred write-back, register-only (used == minv pinned to +inf)
        #pragma unroll
        for (int k = 0; k < NPT; ++k) {
            bool used = (minv[k] == FINF);
            float un = ucol[k] + u_i;
            ur[k] = used ? un : ur[k];
            v[k]  = used ? ((v[k] - u_i) + mcol[k]) : v[k];
        }
        // augment walk, register-only: p[j] = p[way[j]] chain via readlane
        int j = j1;
        while (j != 0) {
            int kj = (j - 1) & 3, oj = (j - 1) >> 2;          // uniform
            int jp = readlane_i(seli4(wayr, kj), oj);         // way[j]
            bool z = (jp == 0);
            int kp = z ? 0 : ((jp - 1) & 3);
            int op = z ? 0 : ((jp - 1) >> 2);
            int   val  = readlane_i(seli4(pl, kp), op);
            float unew = readlane_f(self4(ur, kp), op);
            float pnx  = readlane_f(self4(prx, kp), op);
            float pny  = readlane_f(self4(pry, kp), op);
            float pnz  = readlane_f(self4(prz, kp), op);
            float pnw  = readlane_f(self4(prw, kp), op);
            val  = z ? i     : val;        // p[0] == i
            unew = z ? u_i   : unew;       // u[i] just finalized
            pnx  = z ? pr0.x : pnx;
            pny  = z ? pr0.y : pny;
            pnz  = z ? pr0.z : pnz;
            pnw  = z ? pr0.w : pnw;
            #pragma unroll
            for (int k = 0; k < NPT; ++k) {
                bool hit = (4 * lane + k) == (j - 1);
                pl[k]  = hit ? val  : pl[k];
                ur[k]  = hit ? unew : ur[k];
                prx[k] = hit ? pnx  : prx[k];
                pry[k] = hit ? pny  : pry[k];
                prz[k] = hit ? pnz  : prz[k];
                prw[k] = hit ? pnw  : prw[k];
            }
            j = jp;
        }
    }

    // outputs (float32): col4row[b][r-1] = j ; total_cost[b]
    // IEEE sqrtf here (cost threshold is loose; col4row must be exact).
    float tot = 0.f;
    #pragma unroll
    for (int k = 0; k < NPT; ++k) {
        int j = 4 * lane + k;
        int r = pl[k];                        // 1-based matched row
        out[b * NN + (r - 1)] = (float)j;
        float dx = prx[k] - gx[k], dy = pry[k] - gy[k];
        float dz = prz[k] - gz[k], dw = prw[k] - gw[k];
        tot += sqrtf(dx * dx + dy * dy + dz * dz + dw * dw);
    }
    for (int off = 32; off; off >>= 1) tot += __shfl_xor(tot, off);
    if (lane == 0) out[NB * NN + b] = tot;
}

extern "C" void kernel_launch(void* const* d_in, const int* in_sizes, int n_in,
                              void* d_out, int out_size, void* d_ws, size_t ws_size,
                              hipStream_t stream) {
    const float* pred = (const float*)d_in[0];
    const float* gt   = (const float*)d_in[1];
    float* out = (float*)d_out;
    hipLaunchKernelGGL(hungarian_kernel, dim3(NB), dim3(64), 0, stream,
                       pred, gt, out);
}

// Round 13
// 2107.884 us; speedup vs baseline: 1.1074x; 1.1074x over previous
//
#include <hip/hip_runtime.h>
#include <math.h>

// Batched exact Hungarian (Jonker-Volgenant). One wave per batch; lane l owns
// contiguous columns j = 4l..4l+3 (jj = 4l+k+1): lowest-jj tie-break ==
// prefer-left local tree then lowest-lane ballot == jnp.argmin first-occur.
//
// Round-13 = round-12 design (fully LDS-free, register mirrors + readlane
// augment walk) with the implementation bug fixed: r12's self4/seli4 took
// POINTERS to the per-lane arrays -> SROA failed -> alloca -> backend
// PromoteAlloca put the mirrors in LDS (LDS_Block_Size=5120, 1.6M bank
// conflicts, scratch writes). Here all selects take scalar values (pure
// cndmask trees), so every array stays in VGPRs. Zero __shared__, zero
// barriers, zero LDS instructions expected.
//
// Mirrors per lane (k=0..3): wayr[k]=way[4l+k], pl[k]=p[4l+k+1],
// ur[k]=u[p[..]] (row-start), prx..prw[k]=pred[p[..]], qx..qw[k]=pred[4l+k].
// Walk step: uniform cndmask select + v_readlane. Same mark / deferred-u/v /
// fma+fast-sqrt scan / min3 DPP reduce / ballot+ffs machinery (r8-r11,
// absmax-0-validated).
//
// Output dtype: harness reads d_out as float32; col4row stored as floats.

#define NB   32
#define NN   256
#define ND   4
#define NPT  4
#define INFV 1e9f

#if __has_builtin(__builtin_amdgcn_sqrtf)
__device__ __forceinline__ float fast_sqrtf(float x) { return __builtin_amdgcn_sqrtf(x); }
#else
__device__ __forceinline__ float fast_sqrtf(float x) {
    float r; asm volatile("v_sqrt_f32 %0, %1" : "=v"(r) : "v"(x)); return r;
}
#endif

__device__ __forceinline__ float wave_min_bcast(float x) {
    // 64-lane min in 5 dependent steps (min3 ladder); fill=1e9 never wins.
    const int fill = __float_as_int(INFV);
    int a, c;
    a = __builtin_amdgcn_update_dpp(fill, __float_as_int(x), 0x111, 0xF, 0xF, false); // row_shr:1
    c = __builtin_amdgcn_update_dpp(fill, __float_as_int(x), 0x112, 0xF, 0xF, false); // row_shr:2
    x = fminf(x, fminf(__int_as_float(a), __int_as_float(c)));      // cover 3
    a = __builtin_amdgcn_update_dpp(fill, __float_as_int(x), 0x113, 0xF, 0xF, false); // row_shr:3
    c = __builtin_amdgcn_update_dpp(fill, __float_as_int(x), 0x116, 0xF, 0xF, false); // row_shr:6
    x = fminf(x, fminf(__int_as_float(a), __int_as_float(c)));      // cover 9
    a = __builtin_amdgcn_update_dpp(fill, __float_as_int(x), 0x117, 0xF, 0xF, false); // row_shr:7
    x = fminf(x, __int_as_float(a));                                // cover 16
    a = __builtin_amdgcn_update_dpp(fill, __float_as_int(x), 0x142, 0xF, 0xF, false); // row_bcast:15
    x = fminf(x, __int_as_float(a));
    a = __builtin_amdgcn_update_dpp(fill, __float_as_int(x), 0x143, 0xF, 0xF, false); // row_bcast:31
    x = fminf(x, __int_as_float(a));                                // lane63 = global
    return __int_as_float(__builtin_amdgcn_readlane(__float_as_int(x), 63));
}

__device__ __forceinline__ float readlane_f(float v, int lane) {
    return __int_as_float(__builtin_amdgcn_readlane(__float_as_int(v), lane));
}
__device__ __forceinline__ int readlane_i(int v, int lane) {
    return __builtin_amdgcn_readlane(v, lane);
}
// value-arg selects (NO pointers -> arrays stay SROA'd in VGPRs)
__device__ __forceinline__ float sel4f(float a0, float a1, float a2, float a3, int kk) {
    float u0 = (kk & 1) ? a1 : a0;
    float u1 = (kk & 1) ? a3 : a2;
    return (kk & 2) ? u1 : u0;
}
__device__ __forceinline__ int sel4i(int a0, int a1, int a2, int a3, int kk) {
    int u0 = (kk & 1) ? a1 : a0;
    int u1 = (kk & 1) ? a3 : a2;
    return (kk & 2) ? u1 : u0;
}

__global__ __launch_bounds__(64) void hungarian_kernel(
    const float* __restrict__ pred, const float* __restrict__ gt,
    float* __restrict__ out)
{
#pragma clang fp contract(off)
    const int b    = blockIdx.x;
    const int lane = threadIdx.x;

    const float* pb = pred + (size_t)b * NN * ND;
    const float* gb = gt   + (size_t)b * NN * ND;

    // gt mirrors for owned columns 4l+k, pred-row mirrors for rows 4l+k
    float gx[NPT], gy[NPT], gz[NPT], gw[NPT];
    float qx[NPT], qy[NPT], qz[NPT], qw[NPT];
    #pragma unroll
    for (int k = 0; k < NPT; ++k) {
        float4 gv = ((const float4*)gb)[4 * lane + k];
        gx[k] = gv.x; gy[k] = gv.y; gz[k] = gv.z; gw[k] = gv.w;
        float4 pv = ((const float4*)pb)[4 * lane + k];
        qx[k] = pv.x; qy[k] = pv.y; qz[k] = pv.z; qw[k] = pv.w;
    }
    // column potentials + mirrors of the matched row's u and pred
    float v[NPT], ur[NPT], prx[NPT], pry[NPT], prz[NPT], prw[NPT];
    int pl[NPT];
    #pragma unroll
    for (int k = 0; k < NPT; ++k) {
        v[k] = 0.f; pl[k] = 0; ur[k] = 0.f;
        prx[k] = 0.f; pry[k] = 0.f; prz[k] = 0.f; prw[k] = 0.f;
    }
    const float FINF = __int_as_float(0x7f800000);   // +inf
    const float NINF = __int_as_float(0xff800000);   // -inf

    for (int i = 1; i <= NN; ++i) {
        // row-start: pull pred row i from q-mirrors (wave-uniform owner)
        const int im1 = i - 1, kki = im1 & 3, owi = im1 >> 2;
        float4 pr0;
        pr0.x = readlane_f(sel4f(qx[0], qx[1], qx[2], qx[3], kki), owi);
        pr0.y = readlane_f(sel4f(qy[0], qy[1], qy[2], qy[3], kki), owi);
        pr0.z = readlane_f(sel4f(qz[0], qz[1], qz[2], qz[3], kki), owi);
        pr0.w = readlane_f(sel4f(qw[0], qw[1], qw[2], qw[3], kki), owi);
        float4 pr = pr0;

        int codes[NPT];                    // (jj | pl<<12), constant per row
        #pragma unroll
        for (int k = 0; k < NPT; ++k) codes[k] = (4 * lane + k + 1) | (pl[k] << 12);
        float minv[NPT], vm[NPT], ucol[NPT], mcol[NPT];
        int   wayr[NPT];
        #pragma unroll
        for (int k = 0; k < NPT; ++k) {
            minv[k] = INFV; vm[k] = v[k]; ucol[k] = 0.f; mcol[k] = 0.f; wayr[k] = 0;
        }
        float u_i = 0.f;                          // running sum of deltas == ref u[i]
        int   j1  = 0;
        float ui  = 0.f;                          // u[p[j1]] row-start value
        int   i0n = i;

        for (int it = 0; it < NN + 2; ++it) {
            // branchless mark: jm1=-1 on first iter matches no lane
            const int   jm1 = j1 - 1;             // wave-uniform
            const float bu  = ui - u_i;
            #pragma unroll
            for (int k = 0; k < NPT; ++k) {
                bool hit = (4 * lane + k) == jm1;
                vm[k]   = hit ? NINF : vm[k];     // freezes wayr; cur=+inf
                minv[k] = hit ? FINF : minv[k];   // masks argmin
                ucol[k] = hit ? bu   : ucol[k];   // u_new = ucol + u_i_end
                mcol[k] = hit ? u_i  : mcol[k];   // v_new = (v - u_i_end) + mcol
            }
            // scan owned columns; fma ss + fast sqrt (decisions only)
            #pragma unroll
            for (int k = 0; k < NPT; ++k) {
                float dx = pr.x - gx[k], dy = pr.y - gy[k];
                float dz = pr.z - gz[k], dw = pr.w - gw[k];
                float ss = dx * dx;
                ss = __builtin_fmaf(dy, dy, ss);
                ss = __builtin_fmaf(dz, dz, ss);
                ss = __builtin_fmaf(dw, dw, ss);
                float cur = (fast_sqrtf(ss) - ui) - vm[k];   // used: +inf
                bool upd = cur < minv[k];
                wayr[k] = upd ? j1 : wayr[k];
                minv[k] = fminf(minv[k], cur);
            }
            // 2-level tree argmin with payloads (strict <, prefer-left)
            bool s01 = minv[1] < minv[0];
            float v01 = s01 ? minv[1] : minv[0];
            int   c01 = s01 ? codes[1] : codes[0];
            float u01 = s01 ? ur[1] : ur[0];
            float x01 = s01 ? prx[1] : prx[0];
            float y01 = s01 ? pry[1] : pry[0];
            float z01 = s01 ? prz[1] : prz[0];
            float w01 = s01 ? prw[1] : prw[0];
            bool s23 = minv[3] < minv[2];
            float v23 = s23 ? minv[3] : minv[2];
            int   c23 = s23 ? codes[3] : codes[2];
            float u23 = s23 ? ur[3] : ur[2];
            float x23 = s23 ? prx[3] : prx[2];
            float y23 = s23 ? pry[3] : pry[2];
            float z23 = s23 ? prz[3] : prz[2];
            float w23 = s23 ? prw[3] : prw[2];
            bool sF  = v23 < v01;
            float best       = sF ? v23 : v01;
            int   code_local = sF ? c23 : c01;
            float usel = sF ? u23 : u01;
            float xsel = sF ? x23 : x01;
            float ysel = sF ? y23 : y01;
            float zsel = sF ? z23 : z01;
            float wsel = sF ? w23 : w01;
            // wave argmin: value min via DPP; owner = lowest lane at min
            const float gmin = wave_min_bcast(best);
            unsigned long long msk = __ballot(best == gmin);
            int owner = __ffsll(msk) - 1;
            int code  = readlane_i(code_local, owner);
            int j1n   = code & 0xFFF;
            i0n       = code >> 12;
            // minimal updates: minv -= delta (used stay +inf); u_i += delta
            const float delta = gmin;
            #pragma unroll
            for (int k = 0; k < NPT; ++k) minv[k] -= delta;
            u_i += delta;
            j1 = j1n;
            if (i0n == 0) break;                  // free column (updates done)
            // pull winner's mirrored values (no LDS)
            ui   = readlane_f(usel, owner);
            pr.x = readlane_f(xsel, owner);
            pr.y = readlane_f(ysel, owner);
            pr.z = readlane_f(zsel, owner);
            pr.w = readlane_f(wsel, owner);
        }

        // deferred write-back, register-only (used == minv pinned to +inf)
        #pragma unroll
        for (int k = 0; k < NPT; ++k) {
            bool used = (minv[k] == FINF);
            float un = ucol[k] + u_i;
            ur[k] = used ? un : ur[k];
            v[k]  = used ? ((v[k] - u_i) + mcol[k]) : v[k];
        }
        // augment walk, register-only: p[j] = p[way[j]] chain via readlane
        int j = j1;
        while (j != 0) {
            int kj = (j - 1) & 3, oj = (j - 1) >> 2;          // uniform
            int jp = readlane_i(sel4i(wayr[0], wayr[1], wayr[2], wayr[3], kj), oj);
            bool z = (jp == 0);
            int kp = z ? 0 : ((jp - 1) & 3);
            int op = z ? 0 : ((jp - 1) >> 2);
            int   val  = readlane_i(sel4i(pl[0], pl[1], pl[2], pl[3], kp), op);
            float unew = readlane_f(sel4f(ur[0], ur[1], ur[2], ur[3], kp), op);
            float pnx  = readlane_f(sel4f(prx[0], prx[1], prx[2], prx[3], kp), op);
            float pny  = readlane_f(sel4f(pry[0], pry[1], pry[2], pry[3], kp), op);
            float pnz  = readlane_f(sel4f(prz[0], prz[1], prz[2], prz[3], kp), op);
            float pnw  = readlane_f(sel4f(prw[0], prw[1], prw[2], prw[3], kp), op);
            val  = z ? i     : val;        // p[0] == i
            unew = z ? u_i   : unew;       // u[i] just finalized
            pnx  = z ? pr0.x : pnx;
            pny  = z ? pr0.y : pny;
            pnz  = z ? pr0.z : pnz;
            pnw  = z ? pr0.w : pnw;
            #pragma unroll
            for (int k = 0; k < NPT; ++k) {
                bool hit = (4 * lane + k) == (j - 1);
                pl[k]  = hit ? val  : pl[k];
                ur[k]  = hit ? unew : ur[k];
                prx[k] = hit ? pnx  : prx[k];
                pry[k] = hit ? pny  : pry[k];
                prz[k] = hit ? pnz  : prz[k];
                prw[k] = hit ? pnw  : prw[k];
            }
            j = jp;
        }
    }

    // outputs (float32): col4row[b][r-1] = j ; total_cost[b]
    // IEEE sqrtf here (cost threshold is loose; col4row must be exact).
    float tot = 0.f;
    #pragma unroll
    for (int k = 0; k < NPT; ++k) {
        int j = 4 * lane + k;
        int r = pl[k];                        // 1-based matched row
        out[b * NN + (r - 1)] = (float)j;
        float dx = prx[k] - gx[k], dy = pry[k] - gy[k];
        float dz = prz[k] - gz[k], dw = prw[k] - gw[k];
        tot += sqrtf(dx * dx + dy * dy + dz * dz + dw * dw);
    }
    for (int off = 32; off; off >>= 1) tot += __shfl_xor(tot, off);
    if (lane == 0) out[NB * NN + b] = tot;
}

extern "C" void kernel_launch(void* const* d_in, const int* in_sizes, int n_in,
                              void* d_out, int out_size, void* d_ws, size_t ws_size,
                              hipStream_t stream) {
    const float* pred = (const float*)d_in[0];
    const float* gt   = (const float*)d_in[1];
    float* out = (float*)d_out;
    hipLaunchKernelGGL(hungarian_kernel, dim3(NB), dim3(64), 0, stream,
                       pred, gt, out);
}